// Round 12
// baseline (312.727 us; speedup 1.0000x reference)
//
#include <hip/hip_runtime.h>
#include <hip/hip_bf16.h>

// Attention round 15: 8-wave attn blocks (fatten waves-per-key-tile, NOT q-per-wave).
//  - attn_mfma: 256-q blocks = 8 waves x 32 q (per-wave chain identical to the
//    98us local optimum). K/V 64-key tile now shared by 8 waves -> staging per
//    wave halves (2 gl_lds/tile); grid 512 blocks = exactly 2/CU fully resident;
//    same-CU block pairs share bh (same K/V stream) with balanced nt sums (36).
//  - qkv_mfma (BK=64), out_mfma (BK=64), prep: byte-identical to round 11 (best).
// B=4 S=2048 D=1024 H=16 d=64.
// ws (bf16): Q(prescaled) | K | WoT | {Xbf -> Aout}.
// d_out temp: WcatT @ +512KB (6MB) | V^T @ +8MB (16MB) | EM @ +24MB (8MB).

using bf16 = __hip_bfloat16;
typedef __attribute__((ext_vector_type(8))) short short8;
typedef __attribute__((ext_vector_type(4))) float floatx4;

#define kB 4
#define kS 2048
#define kDM 1024
#define kH 16
#define kDH 64
#define kHeadElems ((size_t)kB * kH * kS * kDH)   /* 8388608 */
#define STR 72

#if __has_builtin(__builtin_amdgcn_exp2f)
#define EXP2(x) __builtin_amdgcn_exp2f(x)
#else
#define EXP2(x) __expf((x) * 0.69314718056f)
#endif

__device__ __forceinline__ unsigned short f2bf(float f) {
    union { float f; unsigned u; } x{f};
    unsigned r = x.u + 0x7fff + ((x.u >> 16) & 1);
    return (unsigned short)(r >> 16);
}
__device__ __forceinline__ unsigned cvt_pk_bf16(float lo, float hi) {
    unsigned r;
    asm("v_cvt_pk_bf16_f32 %0, %1, %2" : "=v"(r) : "v"(lo), "v"(hi));
    return r;
}
__device__ __forceinline__ void gl_lds16(const void* g, void* l) {
    __builtin_amdgcn_global_load_lds(
        (const __attribute__((address_space(1))) unsigned int*)g,
        (__attribute__((address_space(3))) unsigned int*)l, 16, 0, 0);
}

// ---------------------------------------------------------------------------
// prep: blocks [0,1024) = conv_w4 (z = bid>>8); [1024,5120) = conv_x;
//       [5120,7168) = pack_em.
// ---------------------------------------------------------------------------
__global__ __launch_bounds__(256)
void prep(const float* __restrict__ X, bf16* __restrict__ Xb,
          const int* __restrict__ mask_aft, unsigned short* __restrict__ EM,
          const float* __restrict__ Wq, const float* __restrict__ Wk,
          const float* __restrict__ Wv, const float* __restrict__ Wo,
          bf16* __restrict__ WT, bf16* __restrict__ WoT)
{
    __shared__ unsigned short Ls[64][STR];
    const int bid = blockIdx.x;
    const int tid = threadIdx.x;
    if (bid < 1024) {
        const int z = bid >> 8;
        const int rem = bid & 255;
        const float* W = (z == 0) ? Wq : (z == 1) ? Wk : (z == 2) ? Wv : Wo;
        bf16* dst = (z < 3) ? (WT + (size_t)z * kDM * kDM) : WoT;
        const int k0 = (rem & 15) * 64, n0 = (rem >> 4) * 64;
        const int r16 = tid >> 4, c4 = (tid & 15) * 4;
        #pragma unroll
        for (int it = 0; it < 4; ++it) {
            const int r = it * 16 + r16;
            const float4 v = *(const float4*)(W + (size_t)(k0 + r) * kDM + n0 + c4);
            Ls[c4 + 0][r] = f2bf(v.x); Ls[c4 + 1][r] = f2bf(v.y);
            Ls[c4 + 2][r] = f2bf(v.z); Ls[c4 + 3][r] = f2bf(v.w);
        }
        __syncthreads();
        #pragma unroll
        for (int it = 0; it < 4; ++it) {
            const int rn = it * 16 + r16;
            ushort4 u;
            u.x = Ls[rn][c4 + 0]; u.y = Ls[rn][c4 + 1];
            u.z = Ls[rn][c4 + 2]; u.w = Ls[rn][c4 + 3];
            *(ushort4*)(dst + (size_t)(n0 + rn) * kDM + k0 + c4) = u;
        }
    } else if (bid < 5120) {
        const size_t i = ((size_t)(bid - 1024) * 256 + tid) * 8;
        const float4 a = *(const float4*)(X + i);
        const float4 b = *(const float4*)(X + i + 4);
        union { unsigned short u[8]; uint4 v; } o;
        o.u[0] = f2bf(a.x); o.u[1] = f2bf(a.y); o.u[2] = f2bf(a.z); o.u[3] = f2bf(a.w);
        o.u[4] = f2bf(b.x); o.u[5] = f2bf(b.y); o.u[6] = f2bf(b.z); o.u[7] = f2bf(b.w);
        *(uint4*)(Xb + i) = o.v;
    } else {
        const size_t i = ((size_t)(bid - 5120) * 256 + tid) * 8;
        const int q  = (int)(i >> 11);
        const int k0 = (int)(i & 2047);
        const int4 m0 = *(const int4*)(mask_aft + i);
        const int4 m1 = *(const int4*)(mask_aft + i + 4);
        union { unsigned short u[8]; uint4 v; } o;
        o.u[0] = (m0.x || (k0 + 0) > q) ? 0 : 0xFFFFu;
        o.u[1] = (m0.y || (k0 + 1) > q) ? 0 : 0xFFFFu;
        o.u[2] = (m0.z || (k0 + 2) > q) ? 0 : 0xFFFFu;
        o.u[3] = (m0.w || (k0 + 3) > q) ? 0 : 0xFFFFu;
        o.u[4] = (m1.x || (k0 + 4) > q) ? 0 : 0xFFFFu;
        o.u[5] = (m1.y || (k0 + 5) > q) ? 0 : 0xFFFFu;
        o.u[6] = (m1.z || (k0 + 6) > q) ? 0 : 0xFFFFu;
        o.u[7] = (m1.w || (k0 + 7) > q) ? 0 : 0xFFFFu;
        *(uint4*)(EM + i) = o.v;
    }
}

// ---------------------------------------------------------------------------
// qkv_mfma v5 (round-10/11): A[8192][1024] @ WcatT[3072][1024]^T, BK=64
// single-buffer (16 K-steps, 32 MFMA/barrier). XOR chunk swizzle.
// p==0 -> Q (prescaled), p==1 -> K: scatter to ws. p==2 -> V: transposed
// epilogue writes VT[bh][64][2048] via 16KB XOR-swizzled LDS transpose.
// ---------------------------------------------------------------------------
__global__ __launch_bounds__(256)
void qkv_mfma(const bf16* __restrict__ A, const bf16* __restrict__ BT,
              bf16* __restrict__ ws, bf16* __restrict__ VTp)
{
    __shared__ __align__(16) unsigned short SM[16384];              // 32 KB
    unsigned short (*At)[64] = (unsigned short (*)[64])SM;          // [128][64]
    unsigned short (*Bt)[64] = (unsigned short (*)[64])(SM + 8192); // [128][64]
    const int tid = threadIdx.x;
    const int w = tid >> 6, lane = tid & 63;
    const int quad = (tid >> 4) & 3, col = tid & 15;
    const int wm = w >> 1, wn = w & 1;
    const int flat = blockIdx.x + blockIdx.y * 24;
    const int xcd = flat & 7;
    const int i2 = flat >> 3;                  // [0,192)
    const int n0 = (xcd * 3 + (i2 % 3)) * 128;
    const int m0 = (i2 / 3) * 128;

    const int sch = (lane & 7) ^ (lane >> 3);  // staging source-chunk swizzle
    const int c7  = col & 7;                   // read-side row-XOR

    floatx4 acc[4][4];
    #pragma unroll
    for (int i = 0; i < 4; ++i)
        #pragma unroll
        for (int j = 0; j < 4; ++j) acc[i][j] = (floatx4){0.f, 0.f, 0.f, 0.f};

    for (int k0 = 0; k0 < kDM; k0 += 64) {
        __syncthreads();
        #pragma unroll
        for (int t = 0; t < 4; ++t) {
            const int rbase = w * 32 + t * 8;
            const int r = rbase + (lane >> 3);
            gl_lds16(A  + (size_t)(m0 + r) * kDM + k0 + sch * 8, &At[rbase][0]);
            gl_lds16(BT + (size_t)(n0 + r) * kDM + k0 + sch * 8, &Bt[rbase][0]);
        }
        __syncthreads();
        #pragma unroll
        for (int h = 0; h < 2; ++h) {
            const int cc = (h * 4 + quad) ^ c7;
            short8 aA[4], bB[4];
            #pragma unroll
            for (int i = 0; i < 4; ++i)
                aA[i] = *(const short8*)&At[wm * 64 + i * 16 + col][cc * 8];
            #pragma unroll
            for (int j = 0; j < 4; ++j)
                bB[j] = *(const short8*)&Bt[wn * 64 + j * 16 + col][cc * 8];
            #pragma unroll
            for (int i = 0; i < 4; ++i)
                #pragma unroll
                for (int j = 0; j < 4; ++j)
                    acc[i][j] = __builtin_amdgcn_mfma_f32_16x16x32_bf16(aA[i], bB[j], acc[i][j], 0, 0, 0);
        }
    }

    const int p  = n0 >> 10;
    const int nn = n0 & 1023;

    if (p == 2) {
        // ---- V panel: transposed write to VT[bh][64 d][2048 s] ----
        const int bb  = m0 >> 11;
        const int s0b = m0 & 2047;
        const int hA  = nn >> 6;
        #pragma unroll
        for (int hh = 0; hh < 2; ++hh) {
            __syncthreads();
            if (wn == hh) {
                #pragma unroll
                for (int i = 0; i < 4; ++i) {
                    const int s = wm * 64 + i * 16 + quad * 4;
                    #pragma unroll
                    for (int jj = 0; jj < 4; ++jj) {
                        const int d = jj * 16 + col;
                        uint2 pk;
                        pk.x = cvt_pk_bf16(acc[i][jj][0], acc[i][jj][1]);
                        pk.y = cvt_pk_bf16(acc[i][jj][2], acc[i][jj][3]);
                        const int sx = s ^ ((d & 7) << 3);   // bank swizzle
                        *(uint2*)&SM[d * 128 + sx] = pk;
                    }
                }
            }
            __syncthreads();
            bf16* dst = VTp + (size_t)(bb * kH + hA + hh) * kDH * kS;
            #pragma unroll
            for (int k = 0; k < 8; ++k) {
                const int d = k * 8 + (tid >> 5);
                const int s = (tid & 31) * 4;
                const int sx = s ^ ((d & 7) << 3);
                *(uint2*)(dst + (size_t)d * kS + s0b + s) = *(const uint2*)&SM[d * 128 + sx];
            }
        }
        return;
    }

    const float scl = (p == 0) ? 0.18033688f : 1.0f;   // 0.125 * log2(e)
    bf16* Out = ws + (size_t)p * kHeadElems;
    #pragma unroll
    for (int i = 0; i < 4; ++i) {
        #pragma unroll
        for (int r = 0; r < 4; ++r) {
            const int m = m0 + wm * 64 + i * 16 + quad * 4 + r;
            const int b = m >> 11, s = m & 2047;
            #pragma unroll
            for (int j = 0; j < 4; ++j) {
                const int n = nn + wn * 64 + j * 16 + col;
                const int h = n >> 6, d = n & 63;
                Out[((size_t)(b * kH + h) * kS + s) * kDH + d] = __float2bfloat16(acc[i][j][r] * scl);
            }
        }
    }
}

// ---------------------------------------------------------------------------
// attn_mfma v10: 256-q blocks, 8 waves x 32 q (per-wave chain identical to the
// 98us optimum). grid (8, 64) = 512 blocks = exactly 2/CU, fully resident.
// Same-CU block pairs share bh; qtile pairs (7-j, j-4) -> nt sums = 36/CU.
// Staging: 2 gl_lds per wave per tile (was 4).
// ---------------------------------------------------------------------------
__global__ __launch_bounds__(512, 4)
void attn_mfma(const bf16* __restrict__ ws, const bf16* __restrict__ VT,
               const unsigned short* __restrict__ EM,
               bf16* __restrict__ Aout)
{
    const int flat = blockIdx.x + blockIdx.y * 8;
    const int xcd = flat & 7;
    const int idx = flat >> 3;                 // [0,64)
    const int bh  = xcd * 8 + (idx & 7);
    const int j   = idx >> 3;                  // [0,8)
    const int tq  = (j < 4) ? (7 - j) : (j - 4);
    const int q0 = tq * 256;

    const int b = bh >> 4, h = bh & 15;
    const int tid  = threadIdx.x;
    const int w    = tid >> 6;                 // [0,8)
    const int lane = tid & 63;
    const int quad = (tid >> 4) & 3;
    const int col  = tid & 15;

    const size_t ho = (size_t)bh * kS * kDH;
    const bf16* Qg  = ws + ho;                 // pre-scaled by 0.125*log2e
    const bf16* Kg  = ws + kHeadElems + ho;
    const bf16* VTg = VT + ho;                 // [64 d][2048 s]

    __shared__ __align__(16) unsigned short Ks[2][64][64];   // 16 KB, swizzled chunks
    __shared__ __align__(16) unsigned short Vs[2][64][64];   // 16 KB
    __shared__ __align__(16) unsigned short Pw[8][2][16][STR];  // 36.9 KB

    const int qw = q0 + w * 32;
    const int swz = col & 7;                    // read-side XOR swizzle
    const int sch = (lane & 7) ^ (lane >> 3);   // staging source-chunk swizzle

    // Q B-fragments for both 16-row subtiles (n=q=col, k=d)
    short8 bQ[2][2];
    const unsigned short* EMq[2];
    #pragma unroll
    for (int sub = 0; sub < 2; ++sub) {
        const bf16* qrow = Qg + (size_t)(qw + sub * 16 + col) * kDH;
        bQ[sub][0] = *(const short8*)(qrow + quad * 8);
        bQ[sub][1] = *(const short8*)(qrow + 32 + quad * 8);
        EMq[sub] = EM + (size_t)(qw + sub * 16 + col) * kS;
    }

    floatx4 Ov[2][4];
    #pragma unroll
    for (int sub = 0; sub < 2; ++sub)
        #pragma unroll
        for (int dg = 0; dg < 4; ++dg) Ov[sub][dg] = (floatx4){0.f, 0.f, 0.f, 0.f};
    float lacc[2] = {0.f, 0.f};

    const int nt = tq * 4 + 4;                  // block-uniform tile count

    // cooperative stage of tile kt into buffer buf (2 gl_lds per wave)
    auto STAGE = [&](int buf, int kt) {
        const bf16* Kt = Kg  + (size_t)(kt * 64) * kDH;
        const bf16* Vt = VTg + kt * 64;
        const int rbase = w * 8;
        const int r = rbase + (lane >> 3);
        gl_lds16(Kt + (size_t)r * kDH + sch * 8, &Ks[buf][rbase][0]);
        gl_lds16(Vt + (size_t)r * kS  + sch * 8, &Vs[buf][rbase][0]);
    };

    STAGE(0, 0);
    asm volatile("s_waitcnt vmcnt(0)" ::: "memory");
    __builtin_amdgcn_s_barrier();
    __builtin_amdgcn_sched_barrier(0);

    int cur = 0;
    for (int kt = 0; kt < nt; ++kt) {
        const int kt64 = kt * 64;
        const bool doC = (kt64 <= qw + 31);     // wave-uniform compute guard

        // EM loads for THIS tile, issued BEFORE the new staging loads.
        uint2 em[2][4];
        if (doC) {
            #pragma unroll
            for (int sub = 0; sub < 2; ++sub)
                #pragma unroll
                for (int g = 0; g < 4; ++g)
                    em[sub][g] = *(const uint2*)(EMq[sub] + kt64 + g * 16 + quad * 4);
            __builtin_amdgcn_sched_barrier(0);  // pin EM-issue before STAGE
        }

        if (kt + 1 < nt) STAGE(cur ^ 1, kt + 1);   // depth-1 prefetch

        if (doC) {
            // ---- S^T = K Q^T : A=K rows (LDS), B=Q regs; C: row=key, col=q ----
            floatx4 sg[2][4];
            __builtin_amdgcn_s_setprio(1);
            #pragma unroll
            for (int g = 0; g < 4; ++g) {
                const int krow = g * 16 + col;
                const short8 aK0 = *(const short8*)&Ks[cur][krow][(quad ^ swz) * 8];
                const short8 aK1 = *(const short8*)&Ks[cur][krow][((4 + quad) ^ swz) * 8];
                floatx4 sA = {0.f, 0.f, 0.f, 0.f}, sB = {0.f, 0.f, 0.f, 0.f};
                sA = __builtin_amdgcn_mfma_f32_16x16x32_bf16(aK0, bQ[0][0], sA, 0, 0, 0);
                sA = __builtin_amdgcn_mfma_f32_16x16x32_bf16(aK1, bQ[0][1], sA, 0, 0, 0);
                sB = __builtin_amdgcn_mfma_f32_16x16x32_bf16(aK0, bQ[1][0], sB, 0, 0, 0);
                sB = __builtin_amdgcn_mfma_f32_16x16x32_bf16(aK1, bQ[1][1], sB, 0, 0, 0);
                sg[0][g] = sA; sg[1][g] = sB;
            }
            __builtin_amdgcn_s_setprio(0);

            // ---- softmax numerator (exp2), cvt_pk pack, AND expanded mask ----
            #pragma unroll
            for (int sub = 0; sub < 2; ++sub) {
                const int qbase = qw + sub * 16;
                const bool needC = (kt64 + 63 > qbase);
                float lc = 0.f;
                #pragma unroll
                for (int g = 0; g < 4; ++g) {
                    const float p0 = EXP2(sg[sub][g][0]);
                    const float p1 = EXP2(sg[sub][g][1]);
                    const float p2 = EXP2(sg[sub][g][2]);
                    const float p3 = EXP2(sg[sub][g][3]);
                    if (needC) {
                        const int kb = kt64 + g * 16 + quad * 4;
                        const int qme = qbase + col;
                        lc += (kb + 0 <= qme) ? p0 : 0.f;
                        lc += (kb + 1 <= qme) ? p1 : 0.f;
                        lc += (kb + 2 <= qme) ? p2 : 0.f;
                        lc += (kb + 3 <= qme) ? p3 : 0.f;
                    } else {
                        lc += (p0 + p1) + (p2 + p3);
                    }
                    uint2 pk;
                    pk.x = cvt_pk_bf16(p0, p1) & em[sub][g].x;
                    pk.y = cvt_pk_bf16(p2, p3) & em[sub][g].y;
                    *(uint2*)&Pw[w][sub][col][g * 16 + quad * 4] = pk;
                }
                lacc[sub] += lc;
            }

            // ---- O += P V : A=P (wave-private LDS), B=V^T rows (LDS) ----
            const short8 aP[2][2] = {
                { *(const short8*)&Pw[w][0][col][quad * 8],
                  *(const short8*)&Pw[w][0][col][32 + quad * 8] },
                { *(const short8*)&Pw[w][1][col][quad * 8],
                  *(const short8*)&Pw[w][1][col][32 + quad * 8] } };
            __builtin_amdgcn_s_setprio(1);
            #pragma unroll
            for (int dg = 0; dg < 4; ++dg) {
                const int vrow = dg * 16 + col;
                const short8 bV0 = *(const short8*)&Vs[cur][vrow][(quad ^ swz) * 8];
                const short8 bV1 = *(const short8*)&Vs[cur][vrow][((4 + quad) ^ swz) * 8];
                Ov[0][dg] = __builtin_amdgcn_mfma_f32_16x16x32_bf16(aP[0][0], bV0, Ov[0][dg], 0, 0, 0);
                Ov[0][dg] = __builtin_amdgcn_mfma_f32_16x16x32_bf16(aP[0][1], bV1, Ov[0][dg], 0, 0, 0);
                Ov[1][dg] = __builtin_amdgcn_mfma_f32_16x16x32_bf16(aP[1][0], bV0, Ov[1][dg], 0, 0, 0);
                Ov[1][dg] = __builtin_amdgcn_mfma_f32_16x16x32_bf16(aP[1][1], bV1, Ov[1][dg], 0, 0, 0);
            }
            __builtin_amdgcn_s_setprio(0);
        }

        asm volatile("s_waitcnt vmcnt(0)" ::: "memory");   // staged tile landed
        __builtin_amdgcn_s_barrier();
        __builtin_amdgcn_sched_barrier(0);
        cur ^= 1;
    }

    // ---- normalize and write ----
    #pragma unroll
    for (int sub = 0; sub < 2; ++sub) {
        float l = lacc[sub];
        l += __shfl_xor(l, 16, 64);
        l += __shfl_xor(l, 32, 64);
        const float linv = 1.f / l;
        #pragma unroll
        for (int r = 0; r < 4; ++r) {
            const float sc = __shfl(linv, quad * 4 + r, 64);
            const int q = qw + sub * 16 + quad * 4 + r;
            bf16* orow = Aout + ((size_t)(b * kS + q)) * kDM + h * kDH;
            #pragma unroll
            for (int dg = 0; dg < 4; ++dg)
                orow[dg * 16 + col] = __float2bfloat16(Ov[sub][dg][r] * sc);
        }
    }
}

// ---------------------------------------------------------------------------
// out_mfma v2 (round-11): Aout bf16 @ WoT^T -> fp32, BK=64 single-buffer.
// XCD-local: n-panel per XCD.
// ---------------------------------------------------------------------------
__global__ __launch_bounds__(256)
void out_mfma(const bf16* __restrict__ A, const bf16* __restrict__ BT,
              float* __restrict__ Out)
{
    __shared__ __align__(16) unsigned short At[128][64];   // 16 KB
    __shared__ __align__(16) unsigned short Bt[128][64];   // 16 KB
    const int tid = threadIdx.x;
    const int w = tid >> 6, lane = tid & 63;
    const int quad = (tid >> 4) & 3, col = tid & 15;
    const int wm = w >> 1, wn = w & 1;
    const int flat = blockIdx.x + blockIdx.y * 8;
    const int n0 = (flat & 7) * 128;
    const int m0 = (flat >> 3) * 128;

    const int sch = (lane & 7) ^ (lane >> 3);  // staging source-chunk swizzle
    const int c7  = col & 7;                   // read-side row-XOR

    floatx4 acc[4][4];
    #pragma unroll
    for (int i = 0; i < 4; ++i)
        #pragma unroll
        for (int j = 0; j < 4; ++j) acc[i][j] = (floatx4){0.f, 0.f, 0.f, 0.f};

    for (int k0 = 0; k0 < kDM; k0 += 64) {
        __syncthreads();
        #pragma unroll
        for (int t = 0; t < 4; ++t) {
            const int rbase = w * 32 + t * 8;
            const int r = rbase + (lane >> 3);
            gl_lds16(A  + (size_t)(m0 + r) * kDM + k0 + sch * 8, &At[rbase][0]);
            gl_lds16(BT + (size_t)(n0 + r) * kDM + k0 + sch * 8, &Bt[rbase][0]);
        }
        __syncthreads();
        #pragma unroll
        for (int h = 0; h < 2; ++h) {
            const int cc = (h * 4 + quad) ^ c7;
            short8 aA[4], bB[4];
            #pragma unroll
            for (int i = 0; i < 4; ++i)
                aA[i] = *(const short8*)&At[wm * 64 + i * 16 + col][cc * 8];
            #pragma unroll
            for (int j = 0; j < 4; ++j)
                bB[j] = *(const short8*)&Bt[wn * 64 + j * 16 + col][cc * 8];
            #pragma unroll
            for (int i = 0; i < 4; ++i)
                #pragma unroll
                for (int j = 0; j < 4; ++j)
                    acc[i][j] = __builtin_amdgcn_mfma_f32_16x16x32_bf16(aA[i], bB[j], acc[i][j], 0, 0, 0);
        }
    }

    #pragma unroll
    for (int i = 0; i < 4; ++i)
        #pragma unroll
        for (int r = 0; r < 4; ++r) {
            const int m = m0 + wm * 64 + i * 16 + quad * 4 + r;
            #pragma unroll
            for (int j = 0; j < 4; ++j)
                Out[(size_t)m * kDM + n0 + wn * 64 + j * 16 + col] = acc[i][j][r];
        }
}

// ---------------------------------------------------------------------------
extern "C" void kernel_launch(void* const* d_in, const int* in_sizes, int n_in,
                              void* d_out, int out_size, void* d_ws, size_t ws_size,
                              hipStream_t stream)
{
    const float* Xq       = (const float*)d_in[0];
    // d_in[1] = mask_bef (causal, analytic — unused)
    const int*   mask_aft = (const int*)d_in[2];
    const float* Wq       = (const float*)d_in[3];
    const float* Wk       = (const float*)d_in[4];
    const float* Wv       = (const float*)d_in[5];
    const float* Wo       = (const float*)d_in[6];
    float* out = (float*)d_out;

    bf16* ws   = (bf16*)d_ws;
    bf16* Xbf  = ws + 3 * kHeadElems;      // aliased: Xbf (qkv input) -> Aout (attn output)
    bf16* Aout = Xbf;
    bf16* WoT  = ws + 2 * kHeadElems;      // former V slot — free from t=0

    bf16* WcatT = (bf16*)d_out + 262144;                                   // +512KB, 6MB
    bf16* VT    = (bf16*)((char*)d_out + 8u * 1024 * 1024);                // +8MB, 16MB
    unsigned short* EMp = (unsigned short*)((char*)d_out + 24u * 1024 * 1024); // +24MB, 8MB

    prep    <<<dim3(7168), 256, 0, stream>>>(Xq, Xbf, mask_aft, EMp,
                                             Wq, Wk, Wv, Wo, WcatT, WoT);
    qkv_mfma<<<dim3(24, 64), 256, 0, stream>>>(Xbf, WcatT, ws, VT);
    attn_mfma<<<dim3(8, 64), 512, 0, stream>>>(ws, VT, EMp, Aout);
    out_mfma<<<dim3(8, 64), 256, 0, stream>>>(Aout, WoT, out);
}

// Round 13
// 299.085 us; speedup vs baseline: 1.0456x; 1.0456x over previous
//
#include <hip/hip_runtime.h>
#include <hip/hip_bf16.h>

// Attention round 16: round-11 restored (best, 299.9us) + out_mfma 4-blocks/CU.
//  - attn_mfma: EXACT round-8/10/11 kernel (98us local optimum; r4/r6/r9/r12
//    structural variants all regressed).
//  - qkv_mfma: round-10/11 BK=64 kernel. prep: round-11 fused kernel.
//  - out_mfma: tile 128x128 -> 64x128 (grid 512->1024 = 4 blocks/CU, LDS
//    32->24KB, acc[2][4]). Concurrency lever (r5/r8-proven) applied to the
//    last 2-block/CU kernel; per-element K-accumulation order unchanged.
// B=4 S=2048 D=1024 H=16 d=64.
// ws (bf16): Q(prescaled) | K | WoT | {Xbf -> Aout}.
// d_out temp: WcatT @ +512KB (6MB) | V^T @ +8MB (16MB) | EM @ +24MB (8MB).

using bf16 = __hip_bfloat16;
typedef __attribute__((ext_vector_type(8))) short short8;
typedef __attribute__((ext_vector_type(4))) float floatx4;

#define kB 4
#define kS 2048
#define kDM 1024
#define kH 16
#define kDH 64
#define kHeadElems ((size_t)kB * kH * kS * kDH)   /* 8388608 */
#define STR 72

#if __has_builtin(__builtin_amdgcn_exp2f)
#define EXP2(x) __builtin_amdgcn_exp2f(x)
#else
#define EXP2(x) __expf((x) * 0.69314718056f)
#endif

__device__ __forceinline__ unsigned short f2bf(float f) {
    union { float f; unsigned u; } x{f};
    unsigned r = x.u + 0x7fff + ((x.u >> 16) & 1);
    return (unsigned short)(r >> 16);
}
__device__ __forceinline__ unsigned cvt_pk_bf16(float lo, float hi) {
    unsigned r;
    asm("v_cvt_pk_bf16_f32 %0, %1, %2" : "=v"(r) : "v"(lo), "v"(hi));
    return r;
}
__device__ __forceinline__ void gl_lds16(const void* g, void* l) {
    __builtin_amdgcn_global_load_lds(
        (const __attribute__((address_space(1))) unsigned int*)g,
        (__attribute__((address_space(3))) unsigned int*)l, 16, 0, 0);
}

// ---------------------------------------------------------------------------
// prep: blocks [0,1024) = conv_w4 (z = bid>>8); [1024,5120) = conv_x;
//       [5120,7168) = pack_em.
// ---------------------------------------------------------------------------
__global__ __launch_bounds__(256)
void prep(const float* __restrict__ X, bf16* __restrict__ Xb,
          const int* __restrict__ mask_aft, unsigned short* __restrict__ EM,
          const float* __restrict__ Wq, const float* __restrict__ Wk,
          const float* __restrict__ Wv, const float* __restrict__ Wo,
          bf16* __restrict__ WT, bf16* __restrict__ WoT)
{
    __shared__ unsigned short Ls[64][STR];
    const int bid = blockIdx.x;
    const int tid = threadIdx.x;
    if (bid < 1024) {
        const int z = bid >> 8;
        const int rem = bid & 255;
        const float* W = (z == 0) ? Wq : (z == 1) ? Wk : (z == 2) ? Wv : Wo;
        bf16* dst = (z < 3) ? (WT + (size_t)z * kDM * kDM) : WoT;
        const int k0 = (rem & 15) * 64, n0 = (rem >> 4) * 64;
        const int r16 = tid >> 4, c4 = (tid & 15) * 4;
        #pragma unroll
        for (int it = 0; it < 4; ++it) {
            const int r = it * 16 + r16;
            const float4 v = *(const float4*)(W + (size_t)(k0 + r) * kDM + n0 + c4);
            Ls[c4 + 0][r] = f2bf(v.x); Ls[c4 + 1][r] = f2bf(v.y);
            Ls[c4 + 2][r] = f2bf(v.z); Ls[c4 + 3][r] = f2bf(v.w);
        }
        __syncthreads();
        #pragma unroll
        for (int it = 0; it < 4; ++it) {
            const int rn = it * 16 + r16;
            ushort4 u;
            u.x = Ls[rn][c4 + 0]; u.y = Ls[rn][c4 + 1];
            u.z = Ls[rn][c4 + 2]; u.w = Ls[rn][c4 + 3];
            *(ushort4*)(dst + (size_t)(n0 + rn) * kDM + k0 + c4) = u;
        }
    } else if (bid < 5120) {
        const size_t i = ((size_t)(bid - 1024) * 256 + tid) * 8;
        const float4 a = *(const float4*)(X + i);
        const float4 b = *(const float4*)(X + i + 4);
        union { unsigned short u[8]; uint4 v; } o;
        o.u[0] = f2bf(a.x); o.u[1] = f2bf(a.y); o.u[2] = f2bf(a.z); o.u[3] = f2bf(a.w);
        o.u[4] = f2bf(b.x); o.u[5] = f2bf(b.y); o.u[6] = f2bf(b.z); o.u[7] = f2bf(b.w);
        *(uint4*)(Xb + i) = o.v;
    } else {
        const size_t i = ((size_t)(bid - 5120) * 256 + tid) * 8;
        const int q  = (int)(i >> 11);
        const int k0 = (int)(i & 2047);
        const int4 m0 = *(const int4*)(mask_aft + i);
        const int4 m1 = *(const int4*)(mask_aft + i + 4);
        union { unsigned short u[8]; uint4 v; } o;
        o.u[0] = (m0.x || (k0 + 0) > q) ? 0 : 0xFFFFu;
        o.u[1] = (m0.y || (k0 + 1) > q) ? 0 : 0xFFFFu;
        o.u[2] = (m0.z || (k0 + 2) > q) ? 0 : 0xFFFFu;
        o.u[3] = (m0.w || (k0 + 3) > q) ? 0 : 0xFFFFu;
        o.u[4] = (m1.x || (k0 + 4) > q) ? 0 : 0xFFFFu;
        o.u[5] = (m1.y || (k0 + 5) > q) ? 0 : 0xFFFFu;
        o.u[6] = (m1.z || (k0 + 6) > q) ? 0 : 0xFFFFu;
        o.u[7] = (m1.w || (k0 + 7) > q) ? 0 : 0xFFFFu;
        *(uint4*)(EM + i) = o.v;
    }
}

// ---------------------------------------------------------------------------
// qkv_mfma v5 (round-10/11): A[8192][1024] @ WcatT[3072][1024]^T, BK=64
// single-buffer (16 K-steps, 32 MFMA/barrier). XOR chunk swizzle.
// p==0 -> Q (prescaled), p==1 -> K: scatter to ws. p==2 -> V: transposed
// epilogue writes VT[bh][64][2048] via 16KB XOR-swizzled LDS transpose.
// ---------------------------------------------------------------------------
__global__ __launch_bounds__(256)
void qkv_mfma(const bf16* __restrict__ A, const bf16* __restrict__ BT,
              bf16* __restrict__ ws, bf16* __restrict__ VTp)
{
    __shared__ __align__(16) unsigned short SM[16384];              // 32 KB
    unsigned short (*At)[64] = (unsigned short (*)[64])SM;          // [128][64]
    unsigned short (*Bt)[64] = (unsigned short (*)[64])(SM + 8192); // [128][64]
    const int tid = threadIdx.x;
    const int w = tid >> 6, lane = tid & 63;
    const int quad = (tid >> 4) & 3, col = tid & 15;
    const int wm = w >> 1, wn = w & 1;
    const int flat = blockIdx.x + blockIdx.y * 24;
    const int xcd = flat & 7;
    const int i2 = flat >> 3;                  // [0,192)
    const int n0 = (xcd * 3 + (i2 % 3)) * 128;
    const int m0 = (i2 / 3) * 128;

    const int sch = (lane & 7) ^ (lane >> 3);  // staging source-chunk swizzle
    const int c7  = col & 7;                   // read-side row-XOR

    floatx4 acc[4][4];
    #pragma unroll
    for (int i = 0; i < 4; ++i)
        #pragma unroll
        for (int j = 0; j < 4; ++j) acc[i][j] = (floatx4){0.f, 0.f, 0.f, 0.f};

    for (int k0 = 0; k0 < kDM; k0 += 64) {
        __syncthreads();
        #pragma unroll
        for (int t = 0; t < 4; ++t) {
            const int rbase = w * 32 + t * 8;
            const int r = rbase + (lane >> 3);
            gl_lds16(A  + (size_t)(m0 + r) * kDM + k0 + sch * 8, &At[rbase][0]);
            gl_lds16(BT + (size_t)(n0 + r) * kDM + k0 + sch * 8, &Bt[rbase][0]);
        }
        __syncthreads();
        #pragma unroll
        for (int h = 0; h < 2; ++h) {
            const int cc = (h * 4 + quad) ^ c7;
            short8 aA[4], bB[4];
            #pragma unroll
            for (int i = 0; i < 4; ++i)
                aA[i] = *(const short8*)&At[wm * 64 + i * 16 + col][cc * 8];
            #pragma unroll
            for (int j = 0; j < 4; ++j)
                bB[j] = *(const short8*)&Bt[wn * 64 + j * 16 + col][cc * 8];
            #pragma unroll
            for (int i = 0; i < 4; ++i)
                #pragma unroll
                for (int j = 0; j < 4; ++j)
                    acc[i][j] = __builtin_amdgcn_mfma_f32_16x16x32_bf16(aA[i], bB[j], acc[i][j], 0, 0, 0);
        }
    }

    const int p  = n0 >> 10;
    const int nn = n0 & 1023;

    if (p == 2) {
        // ---- V panel: transposed write to VT[bh][64 d][2048 s] ----
        const int bb  = m0 >> 11;
        const int s0b = m0 & 2047;
        const int hA  = nn >> 6;
        #pragma unroll
        for (int hh = 0; hh < 2; ++hh) {
            __syncthreads();
            if (wn == hh) {
                #pragma unroll
                for (int i = 0; i < 4; ++i) {
                    const int s = wm * 64 + i * 16 + quad * 4;
                    #pragma unroll
                    for (int jj = 0; jj < 4; ++jj) {
                        const int d = jj * 16 + col;
                        uint2 pk;
                        pk.x = cvt_pk_bf16(acc[i][jj][0], acc[i][jj][1]);
                        pk.y = cvt_pk_bf16(acc[i][jj][2], acc[i][jj][3]);
                        const int sx = s ^ ((d & 7) << 3);   // bank swizzle
                        *(uint2*)&SM[d * 128 + sx] = pk;
                    }
                }
            }
            __syncthreads();
            bf16* dst = VTp + (size_t)(bb * kH + hA + hh) * kDH * kS;
            #pragma unroll
            for (int k = 0; k < 8; ++k) {
                const int d = k * 8 + (tid >> 5);
                const int s = (tid & 31) * 4;
                const int sx = s ^ ((d & 7) << 3);
                *(uint2*)(dst + (size_t)d * kS + s0b + s) = *(const uint2*)&SM[d * 128 + sx];
            }
        }
        return;
    }

    const float scl = (p == 0) ? 0.18033688f : 1.0f;   // 0.125 * log2(e)
    bf16* Out = ws + (size_t)p * kHeadElems;
    #pragma unroll
    for (int i = 0; i < 4; ++i) {
        #pragma unroll
        for (int r = 0; r < 4; ++r) {
            const int m = m0 + wm * 64 + i * 16 + quad * 4 + r;
            const int b = m >> 11, s = m & 2047;
            #pragma unroll
            for (int j = 0; j < 4; ++j) {
                const int n = nn + wn * 64 + j * 16 + col;
                const int h = n >> 6, d = n & 63;
                Out[((size_t)(b * kH + h) * kS + s) * kDH + d] = __float2bfloat16(acc[i][j][r] * scl);
            }
        }
    }
}

// ---------------------------------------------------------------------------
// attn_mfma v7 (round-8/10/11, best measured): balanced qtile map + K+V
// 2-buffer depth-1 pipeline, 3 blocks/CU. grid (16, 64), block 256.
// ---------------------------------------------------------------------------
__global__ __launch_bounds__(256, 3)
void attn_mfma(const bf16* __restrict__ ws, const bf16* __restrict__ VT,
               const unsigned short* __restrict__ EM,
               bf16* __restrict__ Aout)
{
    // XCD-grouped remap: xcd = flat%8 owns bh in [xcd*8, xcd*8+8) -> K+V 4MB = one L2.
    // qtile(k=j>>2, r=j&3) = 4*(3-k) + ((3-k+r)&3): per-CU qtile sums == 30
    // (balanced 68 tiles/CU), bijective, heavy tiles dispatched first.
    const int flat = blockIdx.x + blockIdx.y * 16;
    const int xcd = flat & 7;
    const int idx = flat >> 3;                 // [0,128)
    const int bh  = xcd * 8 + (idx & 7);
    const int j   = idx >> 3;                  // [0,16)
    const int kk  = 3 - (j >> 2);
    const int qtile = 4 * kk + ((kk + (j & 3)) & 3);
    const int q0 = qtile * 128;

    const int b = bh >> 4, h = bh & 15;
    const int tid  = threadIdx.x;
    const int w    = tid >> 6;
    const int lane = tid & 63;
    const int quad = (tid >> 4) & 3;
    const int col  = tid & 15;

    const size_t ho = (size_t)bh * kS * kDH;
    const bf16* Qg  = ws + ho;                 // pre-scaled by 0.125*log2e
    const bf16* Kg  = ws + kHeadElems + ho;
    const bf16* VTg = VT + ho;                 // [64 d][2048 s]

    __shared__ __align__(16) unsigned short Ks[2][64][64];   // XOR-swizzled chunks
    __shared__ __align__(16) unsigned short Vs[2][64][64];
    __shared__ __align__(16) unsigned short Pw[4][2][16][STR];

    const int qw = q0 + w * 32;
    const int swz = col & 7;                    // read-side XOR swizzle
    const int sch = (lane & 7) ^ (lane >> 3);   // staging source-chunk swizzle

    // Q B-fragments for both 16-row subtiles (n=q=col, k=d)
    short8 bQ[2][2];
    const unsigned short* EMq[2];
    #pragma unroll
    for (int sub = 0; sub < 2; ++sub) {
        const bf16* qrow = Qg + (size_t)(qw + sub * 16 + col) * kDH;
        bQ[sub][0] = *(const short8*)(qrow + quad * 8);
        bQ[sub][1] = *(const short8*)(qrow + 32 + quad * 8);
        EMq[sub] = EM + (size_t)(qw + sub * 16 + col) * kS;
    }

    floatx4 Ov[2][4];
    #pragma unroll
    for (int sub = 0; sub < 2; ++sub)
        #pragma unroll
        for (int dg = 0; dg < 4; ++dg) Ov[sub][dg] = (floatx4){0.f, 0.f, 0.f, 0.f};
    float lacc[2] = {0.f, 0.f};

    const int nt = qtile * 2 + 2;               // block-uniform tile count

    // cooperative stage of tile kt into buffer buf (4 gl_lds per wave)
    auto STAGE = [&](int buf, int kt) {
        const bf16* Kt = Kg  + (size_t)(kt * 64) * kDH;
        const bf16* Vt = VTg + kt * 64;
        #pragma unroll
        for (int t = 0; t < 2; ++t) {
            const int rbase = (t * 4 + w) * 8;
            const int r = rbase + (lane >> 3);
            gl_lds16(Kt + (size_t)r * kDH + sch * 8, &Ks[buf][rbase][0]);
            gl_lds16(Vt + (size_t)r * kS  + sch * 8, &Vs[buf][rbase][0]);
        }
    };

    STAGE(0, 0);
    asm volatile("s_waitcnt vmcnt(0)" ::: "memory");
    __builtin_amdgcn_s_barrier();
    __builtin_amdgcn_sched_barrier(0);

    int cur = 0;
    for (int kt = 0; kt < nt; ++kt) {
        const int kt64 = kt * 64;
        const bool doC = (kt64 <= qw + 31);     // wave-uniform compute guard

        // EM loads for THIS tile, issued BEFORE the new staging loads.
        uint2 em[2][4];
        if (doC) {
            #pragma unroll
            for (int sub = 0; sub < 2; ++sub)
                #pragma unroll
                for (int g = 0; g < 4; ++g)
                    em[sub][g] = *(const uint2*)(EMq[sub] + kt64 + g * 16 + quad * 4);
            __builtin_amdgcn_sched_barrier(0);  // pin EM-issue before STAGE
        }

        if (kt + 1 < nt) STAGE(cur ^ 1, kt + 1);   // depth-1 prefetch

        if (doC) {
            // ---- S^T = K Q^T : A=K rows (LDS), B=Q regs; C: row=key, col=q ----
            floatx4 sg[2][4];
            __builtin_amdgcn_s_setprio(1);
            #pragma unroll
            for (int g = 0; g < 4; ++g) {
                const int krow = g * 16 + col;
                const short8 aK0 = *(const short8*)&Ks[cur][krow][(quad ^ swz) * 8];
                const short8 aK1 = *(const short8*)&Ks[cur][krow][((4 + quad) ^ swz) * 8];
                floatx4 sA = {0.f, 0.f, 0.f, 0.f}, sB = {0.f, 0.f, 0.f, 0.f};
                sA = __builtin_amdgcn_mfma_f32_16x16x32_bf16(aK0, bQ[0][0], sA, 0, 0, 0);
                sA = __builtin_amdgcn_mfma_f32_16x16x32_bf16(aK1, bQ[0][1], sA, 0, 0, 0);
                sB = __builtin_amdgcn_mfma_f32_16x16x32_bf16(aK0, bQ[1][0], sB, 0, 0, 0);
                sB = __builtin_amdgcn_mfma_f32_16x16x32_bf16(aK1, bQ[1][1], sB, 0, 0, 0);
                sg[0][g] = sA; sg[1][g] = sB;
            }
            __builtin_amdgcn_s_setprio(0);

            // ---- softmax numerator (exp2), cvt_pk pack, AND expanded mask ----
            #pragma unroll
            for (int sub = 0; sub < 2; ++sub) {
                const int qbase = qw + sub * 16;
                const bool needC = (kt64 + 63 > qbase);
                float lc = 0.f;
                #pragma unroll
                for (int g = 0; g < 4; ++g) {
                    const float p0 = EXP2(sg[sub][g][0]);
                    const float p1 = EXP2(sg[sub][g][1]);
                    const float p2 = EXP2(sg[sub][g][2]);
                    const float p3 = EXP2(sg[sub][g][3]);
                    if (needC) {
                        const int kb = kt64 + g * 16 + quad * 4;
                        const int qme = qbase + col;
                        lc += (kb + 0 <= qme) ? p0 : 0.f;
                        lc += (kb + 1 <= qme) ? p1 : 0.f;
                        lc += (kb + 2 <= qme) ? p2 : 0.f;
                        lc += (kb + 3 <= qme) ? p3 : 0.f;
                    } else {
                        lc += (p0 + p1) + (p2 + p3);
                    }
                    uint2 pk;
                    pk.x = cvt_pk_bf16(p0, p1) & em[sub][g].x;
                    pk.y = cvt_pk_bf16(p2, p3) & em[sub][g].y;
                    *(uint2*)&Pw[w][sub][col][g * 16 + quad * 4] = pk;
                }
                lacc[sub] += lc;
            }

            // ---- O += P V : A=P (wave-private LDS), B=V^T rows (LDS) ----
            const short8 aP[2][2] = {
                { *(const short8*)&Pw[w][0][col][quad * 8],
                  *(const short8*)&Pw[w][0][col][32 + quad * 8] },
                { *(const short8*)&Pw[w][1][col][quad * 8],
                  *(const short8*)&Pw[w][1][col][32 + quad * 8] } };
            __builtin_amdgcn_s_setprio(1);
            #pragma unroll
            for (int dg = 0; dg < 4; ++dg) {
                const int vrow = dg * 16 + col;
                const short8 bV0 = *(const short8*)&Vs[cur][vrow][(quad ^ swz) * 8];
                const short8 bV1 = *(const short8*)&Vs[cur][vrow][((4 + quad) ^ swz) * 8];
                Ov[0][dg] = __builtin_amdgcn_mfma_f32_16x16x32_bf16(aP[0][0], bV0, Ov[0][dg], 0, 0, 0);
                Ov[0][dg] = __builtin_amdgcn_mfma_f32_16x16x32_bf16(aP[0][1], bV1, Ov[0][dg], 0, 0, 0);
                Ov[1][dg] = __builtin_amdgcn_mfma_f32_16x16x32_bf16(aP[1][0], bV0, Ov[1][dg], 0, 0, 0);
                Ov[1][dg] = __builtin_amdgcn_mfma_f32_16x16x32_bf16(aP[1][1], bV1, Ov[1][dg], 0, 0, 0);
            }
            __builtin_amdgcn_s_setprio(0);
        }

        asm volatile("s_waitcnt vmcnt(0)" ::: "memory");   // staged tile landed
        __builtin_amdgcn_s_barrier();
        __builtin_amdgcn_sched_barrier(0);
        cur ^= 1;
    }

    // ---- normalize and write ----
    #pragma unroll
    for (int sub = 0; sub < 2; ++sub) {
        float l = lacc[sub];
        l += __shfl_xor(l, 16, 64);
        l += __shfl_xor(l, 32, 64);
        const float linv = 1.f / l;
        #pragma unroll
        for (int r = 0; r < 4; ++r) {
            const float sc = __shfl(linv, quad * 4 + r, 64);
            const int q = qw + sub * 16 + quad * 4 + r;
            bf16* orow = Aout + ((size_t)(b * kS + q)) * kDM + h * kDH;
            #pragma unroll
            for (int dg = 0; dg < 4; ++dg)
                orow[dg * 16 + col] = __float2bfloat16(Ov[sub][dg][r] * sc);
        }
    }
}

// ---------------------------------------------------------------------------
// out_mfma v3: Aout bf16 @ WoT^T -> fp32. Tile 64m x 128n, BK=64 single-buffer
// -> grid 1024 = 4 blocks/CU (was 2), LDS 24KB, acc[2][4]. Per-element K
// accumulation order unchanged vs v2 (bitwise-identical). XCD-local n-panel.
// ---------------------------------------------------------------------------
__global__ __launch_bounds__(256)
void out_mfma(const bf16* __restrict__ A, const bf16* __restrict__ BT,
              float* __restrict__ Out)
{
    __shared__ __align__(16) unsigned short At[64][64];    //  8 KB
    __shared__ __align__(16) unsigned short Bt[128][64];   // 16 KB
    const int tid = threadIdx.x;
    const int w = tid >> 6, lane = tid & 63;
    const int quad = (tid >> 4) & 3, col = tid & 15;
    const int wm = w >> 1, wn = w & 1;
    const int flat = blockIdx.x + blockIdx.y * 8;
    const int n0 = (flat & 7) * 128;
    const int m0 = (flat >> 3) * 64;

    const int sch = (lane & 7) ^ (lane >> 3);  // staging source-chunk swizzle
    const int c7  = col & 7;                   // read-side row-XOR

    floatx4 acc[2][4];
    #pragma unroll
    for (int i = 0; i < 2; ++i)
        #pragma unroll
        for (int j = 0; j < 4; ++j) acc[i][j] = (floatx4){0.f, 0.f, 0.f, 0.f};

    for (int k0 = 0; k0 < kDM; k0 += 64) {
        __syncthreads();
        #pragma unroll
        for (int t = 0; t < 2; ++t) {
            const int rbase = w * 16 + t * 8;
            const int r = rbase + (lane >> 3);
            gl_lds16(A + (size_t)(m0 + r) * kDM + k0 + sch * 8, &At[rbase][0]);
        }
        #pragma unroll
        for (int t = 0; t < 4; ++t) {
            const int rbase = w * 32 + t * 8;
            const int r = rbase + (lane >> 3);
            gl_lds16(BT + (size_t)(n0 + r) * kDM + k0 + sch * 8, &Bt[rbase][0]);
        }
        __syncthreads();
        #pragma unroll
        for (int h = 0; h < 2; ++h) {
            const int cc = (h * 4 + quad) ^ c7;
            short8 aA[2], bB[4];
            #pragma unroll
            for (int i = 0; i < 2; ++i)
                aA[i] = *(const short8*)&At[wm * 32 + i * 16 + col][cc * 8];
            #pragma unroll
            for (int j = 0; j < 4; ++j)
                bB[j] = *(const short8*)&Bt[wn * 64 + j * 16 + col][cc * 8];
            #pragma unroll
            for (int i = 0; i < 2; ++i)
                #pragma unroll
                for (int j = 0; j < 4; ++j)
                    acc[i][j] = __builtin_amdgcn_mfma_f32_16x16x32_bf16(aA[i], bB[j], acc[i][j], 0, 0, 0);
        }
    }

    #pragma unroll
    for (int i = 0; i < 2; ++i)
        #pragma unroll
        for (int r = 0; r < 4; ++r) {
            const int m = m0 + wm * 32 + i * 16 + quad * 4 + r;
            #pragma unroll
            for (int j = 0; j < 4; ++j)
                Out[(size_t)m * kDM + n0 + wn * 64 + j * 16 + col] = acc[i][j][r];
        }
}

// ---------------------------------------------------------------------------
extern "C" void kernel_launch(void* const* d_in, const int* in_sizes, int n_in,
                              void* d_out, int out_size, void* d_ws, size_t ws_size,
                              hipStream_t stream)
{
    const float* Xq       = (const float*)d_in[0];
    // d_in[1] = mask_bef (causal, analytic — unused)
    const int*   mask_aft = (const int*)d_in[2];
    const float* Wq       = (const float*)d_in[3];
    const float* Wk       = (const float*)d_in[4];
    const float* Wv       = (const float*)d_in[5];
    const float* Wo       = (const float*)d_in[6];
    float* out = (float*)d_out;

    bf16* ws   = (bf16*)d_ws;
    bf16* Xbf  = ws + 3 * kHeadElems;      // aliased: Xbf (qkv input) -> Aout (attn output)
    bf16* Aout = Xbf;
    bf16* WoT  = ws + 2 * kHeadElems;      // former V slot — free from t=0

    bf16* WcatT = (bf16*)d_out + 262144;                                   // +512KB, 6MB
    bf16* VT    = (bf16*)((char*)d_out + 8u * 1024 * 1024);                // +8MB, 16MB
    unsigned short* EMp = (unsigned short*)((char*)d_out + 24u * 1024 * 1024); // +24MB, 8MB

    prep    <<<dim3(7168), 256, 0, stream>>>(Xq, Xbf, mask_aft, EMp,
                                             Wq, Wk, Wv, Wo, WcatT, WoT);
    qkv_mfma<<<dim3(24, 64), 256, 0, stream>>>(Xbf, WcatT, ws, VT);
    attn_mfma<<<dim3(16, 64), 256, 0, stream>>>(ws, VT, EMp, Aout);
    out_mfma<<<dim3(8, 128), 256, 0, stream>>>(Aout, WoT, out);
}